// Round 2
// baseline (130.634 us; speedup 1.0000x reference)
//
#include <hip/hip_runtime.h>

#define BB   4
#define FF   128
#define CC   8
#define LSEQ 196608        // 256*256*3
#define NCH  2048
#define CL   96            // LSEQ / NCH
#define TL   16            // positions per LDS tile in k_final
#define NT   6             // CL / TL
#define NSEG 32
#define SEGL 64            // NCH / NSEG
#define PADF 130           // stile row stride (floats)
#define RS   12            // red row stride (floats), 16B-aligned rows

// ---------------- K1: per-chunk feature sums ----------------
__global__ __launch_bounds__(64) void k_chunksum(
    const int* __restrict__ ex, const float* __restrict__ W_in,
    const float* __restrict__ b_in, const float* __restrict__ pos,
    float* __restrict__ csum)
{
    __shared__ float xv[BB][CL];
    const int ch = blockIdx.x;
    const int t  = threadIdx.x;
    const int l0 = ch * CL;
    #pragma unroll
    for (int b = 0; b < BB; ++b)
        for (int i = t; i < CL; i += 64)
            xv[b][i] = (float)ex[(size_t)b * LSEQ + l0 + i] * 0.5f - 3.0f;
    __syncthreads();

    const float2 w  = *(const float2*)&W_in[2 * t];
    const float2 bb = *(const float2*)&b_in[2 * t];
    float2 s[BB];
    #pragma unroll
    for (int b = 0; b < BB; ++b) { s[b].x = 0.f; s[b].y = 0.f; }
    const float* pp = pos + (size_t)l0 * FF + 2 * t;
    #pragma unroll 4
    for (int l = 0; l < CL; ++l) {
        float2 p = *(const float2*)pp; pp += FF;
        float px = p.x + bb.x, py = p.y + bb.y;
        #pragma unroll
        for (int b = 0; b < BB; ++b) {
            float x = xv[b][l];
            s[b].x += fmaxf(fmaf(x, w.x, px), 0.f);
            s[b].y += fmaxf(fmaf(x, w.y, py), 0.f);
        }
    }
    #pragma unroll
    for (int b = 0; b < BB; ++b)
        *(float2*)&csum[((size_t)b * NCH + ch) * FF + 2 * t] = s[b];
}

// ---------------- K2a: segment totals ----------------
__global__ __launch_bounds__(128) void k_segsum(
    const float* __restrict__ csum, float* __restrict__ segT)
{
    const int seg = blockIdx.x, b = blockIdx.y, f = threadIdx.x;
    const float* p = csum + ((size_t)b * NCH + (size_t)seg * SEGL) * FF + f;
    float a = 0.f;
    #pragma unroll 8
    for (int i = 0; i < SEGL; ++i) a += p[(size_t)i * FF];
    segT[((size_t)b * NSEG + seg) * FF + f] = a;
}

// ---------------- K2b: exclusive scan of segment totals ----------------
__global__ __launch_bounds__(128) void k_segscan(float* __restrict__ segT)
{
    const int b = blockIdx.x, f = threadIdx.x;
    float acc = 0.f;
    for (int s = 0; s < NSEG; ++s) {
        size_t idx = ((size_t)b * NSEG + s) * FF + f;
        float v = segT[idx];
        segT[idx] = acc;
        acc += v;
    }
}

// ---------------- K2c: exclusive-ize chunk sums ----------------
__global__ __launch_bounds__(128) void k_chscan(
    float* __restrict__ csum, const float* __restrict__ segT)
{
    const int seg = blockIdx.x, b = blockIdx.y, f = threadIdx.x;
    float acc = segT[((size_t)b * NSEG + seg) * FF + f];
    float* p = csum + ((size_t)b * NCH + (size_t)seg * SEGL) * FF + f;
    #pragma unroll 8
    for (int i = 0; i < SEGL; ++i) {
        float v = p[(size_t)i * FF];
        p[(size_t)i * FF] = acc;
        acc += v;
    }
}

// ---------------- K3: scan + normalize + final dense ----------------
// 256 threads = 4 waves. Phase A: wave = batch, thread = feature-pair.
// Phase B: wave = 32-feature segment (uniform Wf -> s_loads), lane = item.
// Cross-wave partial reduce through `red`, aliased onto stile.
__global__ __launch_bounds__(256, 4) void k_final(
    const int* __restrict__ ex, const float* __restrict__ W_in,
    const float* __restrict__ b_in, const float* __restrict__ pos,
    const float* __restrict__ Wf, const float* __restrict__ bfin,
    const float* __restrict__ csum, float* __restrict__ out)
{
    __shared__ __align__(16) float stile[BB * TL][PADF];   // 64 x 130 = 33280 B
    __shared__ float xv[BB][CL];
    float* red = &stile[0][0];   // aliased: [4*64][RS] = 3072 floats < 8320

    const int ch = blockIdx.x;
    const int t  = threadIdx.x;
    const int l0 = ch * CL;
    const int b    = t >> 6;          // wave index
    const int f2   = t & 63;          // feature pair (phase A)
    const int lane = t & 63;          // item (phase B)
    const int wseg = __builtin_amdgcn_readfirstlane(b);

    {   // stage example values
        for (int i = lane; i < CL; i += 64)
            xv[b][i] = (float)ex[(size_t)b * LSEQ + l0 + i] * 0.5f - 3.0f;
    }

    const float2 w  = *(const float2*)&W_in[2 * f2];
    const float2 bb = *(const float2*)&b_in[2 * f2];
    float2 s = *(const float2*)&csum[((size_t)b * NCH + ch) * FF + 2 * f2];

    __syncthreads();

    for (int tile = 0; tile < NT; ++tile) {
        // ---- phase A: scan TL positions, thread-per-(batch,feature-pair) ----
        const float* pp = pos + (size_t)(l0 + tile * TL) * FF + 2 * f2;
        #pragma unroll
        for (int l = 0; l < TL; ++l) {
            float2 p = *(const float2*)pp; pp += FF;
            float x = xv[b][tile * TL + l];
            s.x += fmaxf(fmaf(x, w.x, p.x + bb.x), 0.f);
            s.y += fmaxf(fmaf(x, w.y, p.y + bb.y), 0.f);
            *(float2*)&stile[b * TL + l][2 * f2] = s;
        }
        __syncthreads();

        // ---- phase B main: wave=feature segment, lane=item ----
        float acc[CC] = {0.f,0.f,0.f,0.f,0.f,0.f,0.f,0.f};
        float q = 0.f;
        const float* srow = &stile[lane][wseg * 32];
        const float* wfp  = Wf + (size_t)wseg * 32 * CC;   // wave-uniform
        #pragma unroll
        for (int k = 0; k < 16; ++k) {
            float2 v = *(const float2*)&srow[2 * k];
            #pragma unroll
            for (int c = 0; c < CC; ++c)
                acc[c] += v.x * wfp[(2 * k) * CC + c] + v.y * wfp[(2 * k + 1) * CC + c];
            q += v.x * v.x + v.y * v.y;
        }
        __syncthreads();   // all stile reads done before red (alias) writes

        float* rrow = &red[(wseg * 64 + lane) * RS];
        *(float4*)&rrow[0] = make_float4(acc[0], acc[1], acc[2], acc[3]);
        *(float4*)&rrow[4] = make_float4(acc[4], acc[5], acc[6], acc[7]);
        rrow[8] = q;
        __syncthreads();

        // ---- final reduce: thread = (item=lane, out-pair g=wseg) ----
        {
            const int g = wseg;
            float ax = 0.f, ay = 0.f, qq = 0.f;
            #pragma unroll
            for (int ww = 0; ww < 4; ++ww) {
                const float* r2 = &red[(ww * 64 + lane) * RS];
                float2 v = *(const float2*)&r2[2 * g];
                ax += v.x; ay += v.y;
                qq += r2[8];
            }
            float rr = rsqrtf(fmaxf(qq, 1e-12f));
            float2 bfv = *(const float2*)&bfin[2 * g];
            float ox = fmaf(ax, rr, bfv.x);
            float oy = fmaf(ay, rr, bfv.y);
            int bi = lane >> 4, li = lane & 15;
            size_t ob = (((size_t)bi * LSEQ) + l0 + tile * TL + li) * CC + 2 * g;
            *(float2*)&out[ob] = make_float2(ox, oy);
        }
        __syncthreads();   // before next tile's phase A overwrites stile/red
    }
}

extern "C" void kernel_launch(void* const* d_in, const int* in_sizes, int n_in,
                              void* d_out, int out_size, void* d_ws, size_t ws_size,
                              hipStream_t stream) {
    const int*   ex   = (const int*)d_in[0];
    const float* W_in = (const float*)d_in[1];
    const float* b_in = (const float*)d_in[2];
    const float* pos  = (const float*)d_in[3];
    const float* Wf   = (const float*)d_in[4];
    const float* bf   = (const float*)d_in[5];
    float* out  = (float*)d_out;
    float* csum = (float*)d_ws;                       // [B][NCH][F]  = 4 MB
    float* segT = csum + (size_t)BB * NCH * FF;       // [B][NSEG][F] = 64 KB

    k_chunksum<<<NCH, 64, 0, stream>>>(ex, W_in, b_in, pos, csum);
    k_segsum  <<<dim3(NSEG, BB), 128, 0, stream>>>(csum, segT);
    k_segscan <<<BB, 128, 0, stream>>>(segT);
    k_chscan  <<<dim3(NSEG, BB), 128, 0, stream>>>(csum, segT);
    k_final   <<<NCH, 256, 0, stream>>>(ex, W_in, b_in, pos, Wf, bf, csum, out);
}

// Round 3
// 92.734 us; speedup vs baseline: 1.4087x; 1.4087x over previous
//
#include <hip/hip_runtime.h>
#include <hip/hip_fp16.h>

#define BB   4
#define FF   128
#define CC   8
#define LSEQ 196608        // 256*256*3
#define NCH  2048
#define CL   96            // LSEQ / NCH
#define TL   16            // positions per LDS tile in k_final
#define NT   6             // CL / TL
#define NSEG 32
#define SEGL 64            // NCH / NSEG
#define PADH 130           // stile row stride in HALVES = 65 dwords -> bank rotate

// ---------------- K1: per-chunk feature sums ----------------
__global__ __launch_bounds__(64) void k_chunksum(
    const int* __restrict__ ex, const float* __restrict__ W_in,
    const float* __restrict__ b_in, const float* __restrict__ pos,
    float* __restrict__ csum)
{
    __shared__ float xv[BB][CL];
    const int ch = blockIdx.x;
    const int t  = threadIdx.x;
    const int l0 = ch * CL;
    #pragma unroll
    for (int b = 0; b < BB; ++b)
        for (int i = t; i < CL; i += 64)
            xv[b][i] = (float)ex[(size_t)b * LSEQ + l0 + i] * 0.5f - 3.0f;
    __syncthreads();

    const float2 w  = *(const float2*)&W_in[2 * t];
    const float2 bb = *(const float2*)&b_in[2 * t];
    float2 s[BB];
    #pragma unroll
    for (int b = 0; b < BB; ++b) { s[b].x = 0.f; s[b].y = 0.f; }
    const float* pp = pos + (size_t)l0 * FF + 2 * t;
    #pragma unroll 4
    for (int l = 0; l < CL; ++l) {
        float2 p = *(const float2*)pp; pp += FF;
        float px = p.x + bb.x, py = p.y + bb.y;
        #pragma unroll
        for (int b = 0; b < BB; ++b) {
            float x = xv[b][l];
            s[b].x += fmaxf(fmaf(x, w.x, px), 0.f);
            s[b].y += fmaxf(fmaf(x, w.y, py), 0.f);
        }
    }
    #pragma unroll
    for (int b = 0; b < BB; ++b)
        *(float2*)&csum[((size_t)b * NCH + ch) * FF + 2 * t] = s[b];
}

// ---------------- K2a: segment totals ----------------
__global__ __launch_bounds__(128) void k_segsum(
    const float* __restrict__ csum, float* __restrict__ segT)
{
    const int seg = blockIdx.x, b = blockIdx.y, f = threadIdx.x;
    const float* p = csum + ((size_t)b * NCH + (size_t)seg * SEGL) * FF + f;
    float a = 0.f;
    #pragma unroll 8
    for (int i = 0; i < SEGL; ++i) a += p[(size_t)i * FF];
    segT[((size_t)b * NSEG + seg) * FF + f] = a;
}

// ---------------- K2b: exclusive scan of segment totals ----------------
__global__ __launch_bounds__(128) void k_segscan(float* __restrict__ segT)
{
    const int b = blockIdx.x, f = threadIdx.x;
    float acc = 0.f;
    for (int s = 0; s < NSEG; ++s) {
        size_t idx = ((size_t)b * NSEG + s) * FF + f;
        float v = segT[idx];
        segT[idx] = acc;
        acc += v;
    }
}

// ---------------- K2c: exclusive-ize chunk sums ----------------
__global__ __launch_bounds__(128) void k_chscan(
    float* __restrict__ csum, const float* __restrict__ segT)
{
    const int seg = blockIdx.x, b = blockIdx.y, f = threadIdx.x;
    float acc = segT[((size_t)b * NSEG + seg) * FF + f];
    float* p = csum + ((size_t)b * NCH + (size_t)seg * SEGL) * FF + f;
    #pragma unroll 8
    for (int i = 0; i < SEGL; ++i) {
        float v = p[(size_t)i * FF];
        p[(size_t)i * FF] = acc;
        acc += v;
    }
}

// ---------------- K3: scan + normalize + final dense ----------------
// Round-1 structure (thread owns full row in phase B), f16 stile for 2x
// occupancy. Row stride 65 dwords -> bank=(lane+k)%32, 2-way = free.
__global__ __launch_bounds__(64, 2) void k_final(
    const int* __restrict__ ex, const float* __restrict__ W_in,
    const float* __restrict__ b_in, const float* __restrict__ pos,
    const float* __restrict__ Wf, const float* __restrict__ bfin,
    const float* __restrict__ csum, float* __restrict__ out)
{
    __shared__ __align__(4) __half stile[BB * TL][PADH];  // 64 x 260B = 16.6KB
    __shared__ float xv[BB][CL];
    const int ch = blockIdx.x;
    const int t  = threadIdx.x;
    const int l0 = ch * CL;
    #pragma unroll
    for (int b = 0; b < BB; ++b)
        for (int i = t; i < CL; i += 64)
            xv[b][i] = (float)ex[(size_t)b * LSEQ + l0 + i] * 0.5f - 3.0f;
    __syncthreads();

    const float2 w  = *(const float2*)&W_in[2 * t];
    const float2 bb = *(const float2*)&b_in[2 * t];
    float2 s[BB];
    #pragma unroll
    for (int b = 0; b < BB; ++b)
        s[b] = *(const float2*)&csum[((size_t)b * NCH + ch) * FF + 2 * t];

    const int jb = t >> 4;   // batch owned in phase B
    const int jl = t & 15;   // tile-local position owned in phase B

    for (int tile = 0; tile < NT; ++tile) {
        // ---- phase A: scan TL positions, thread = feature-pair, 4 batches ----
        const float* pp = pos + (size_t)(l0 + tile * TL) * FF + 2 * t;
        #pragma unroll
        for (int l = 0; l < TL; ++l) {
            float2 p = *(const float2*)pp; pp += FF;
            float px = p.x + bb.x, py = p.y + bb.y;
            #pragma unroll
            for (int b = 0; b < BB; ++b) {
                float x = xv[b][tile * TL + l];
                s[b].x += fmaxf(fmaf(x, w.x, px), 0.f);
                s[b].y += fmaxf(fmaf(x, w.y, py), 0.f);
                *(__half2*)&stile[b * TL + l][2 * t] =
                    __float22half2_rn(make_float2(s[b].x, s[b].y));
            }
        }
        __syncthreads();

        // ---- phase B: thread-per-(batch,position): norm + 128x8 matvec ----
        float acc[CC] = {0.f,0.f,0.f,0.f,0.f,0.f,0.f,0.f};
        float q = 0.f;
        const __half* srow = &stile[jb * TL + jl][0];
        #pragma unroll 8
        for (int k = 0; k < FF / 2; ++k) {
            float2 v = __half22float2(*(const __half2*)&srow[2 * k]);
            const float* wr = Wf + (2 * k) * CC;   // uniform -> scalar loads
            #pragma unroll
            for (int c = 0; c < CC; ++c)
                acc[c] += v.x * wr[c] + v.y * wr[CC + c];
            q += v.x * v.x + v.y * v.y;
        }
        float r = rsqrtf(fmaxf(q, 1e-12f));
        float o[CC];
        #pragma unroll
        for (int c = 0; c < CC; ++c) o[c] = fmaf(acc[c], r, bfin[c]);
        size_t ob = ((size_t)jb * LSEQ + l0 + tile * TL + jl) * CC;
        *(float4*)&out[ob]     = make_float4(o[0], o[1], o[2], o[3]);
        *(float4*)&out[ob + 4] = make_float4(o[4], o[5], o[6], o[7]);
        __syncthreads();   // before next tile's phase A overwrites stile
    }
}

extern "C" void kernel_launch(void* const* d_in, const int* in_sizes, int n_in,
                              void* d_out, int out_size, void* d_ws, size_t ws_size,
                              hipStream_t stream) {
    const int*   ex   = (const int*)d_in[0];
    const float* W_in = (const float*)d_in[1];
    const float* b_in = (const float*)d_in[2];
    const float* pos  = (const float*)d_in[3];
    const float* Wf   = (const float*)d_in[4];
    const float* bf   = (const float*)d_in[5];
    float* out  = (float*)d_out;
    float* csum = (float*)d_ws;                       // [B][NCH][F]  = 4 MB
    float* segT = csum + (size_t)BB * NCH * FF;       // [B][NSEG][F] = 64 KB

    k_chunksum<<<NCH, 64, 0, stream>>>(ex, W_in, b_in, pos, csum);
    k_segsum  <<<dim3(NSEG, BB), 128, 0, stream>>>(csum, segT);
    k_segscan <<<BB, 128, 0, stream>>>(segT);
    k_chscan  <<<dim3(NSEG, BB), 128, 0, stream>>>(csum, segT);
    k_final   <<<NCH, 64, 0, stream>>>(ex, W_in, b_in, pos, Wf, bf, csum, out);
}

// Round 4
// 69.594 us; speedup vs baseline: 1.8771x; 1.3325x over previous
//
#include <hip/hip_runtime.h>
#include <hip/hip_fp16.h>

#define BB   4
#define FF   128
#define CC   8
#define LSEQ 196608        // 256*256*3
#define NCH  2048
#define CL   96            // LSEQ / NCH
#define TL   16            // positions per tile (= MFMA M)
#define NT   6             // CL / TL
#define NSEG 32
#define SEGL 64            // NCH / NSEG

typedef _Float16 half8 __attribute__((ext_vector_type(8)));
typedef float    f32x4 __attribute__((ext_vector_type(4)));

// ---------------- K1: per-chunk feature sums ----------------
__global__ __launch_bounds__(64) void k_chunksum(
    const int* __restrict__ ex, const float* __restrict__ W_in,
    const float* __restrict__ b_in, const float* __restrict__ pos,
    float* __restrict__ csum)
{
    __shared__ float xv[BB][CL];
    const int ch = blockIdx.x;
    const int t  = threadIdx.x;
    const int l0 = ch * CL;
    #pragma unroll
    for (int b = 0; b < BB; ++b)
        for (int i = t; i < CL; i += 64)
            xv[b][i] = (float)ex[(size_t)b * LSEQ + l0 + i] * 0.5f - 3.0f;
    __syncthreads();

    const float2 w  = *(const float2*)&W_in[2 * t];
    const float2 bb = *(const float2*)&b_in[2 * t];
    float2 s[BB];
    #pragma unroll
    for (int b = 0; b < BB; ++b) { s[b].x = 0.f; s[b].y = 0.f; }
    const float* pp = pos + (size_t)l0 * FF + 2 * t;
    #pragma unroll 4
    for (int l = 0; l < CL; ++l) {
        float2 p = *(const float2*)pp; pp += FF;
        float px = p.x + bb.x, py = p.y + bb.y;
        #pragma unroll
        for (int b = 0; b < BB; ++b) {
            float x = xv[b][l];
            s[b].x += fmaxf(fmaf(x, w.x, px), 0.f);
            s[b].y += fmaxf(fmaf(x, w.y, py), 0.f);
        }
    }
    #pragma unroll
    for (int b = 0; b < BB; ++b)
        *(float2*)&csum[((size_t)b * NCH + ch) * FF + 2 * t] = s[b];
}

// ---------------- K2a: segment totals ----------------
__global__ __launch_bounds__(128) void k_segsum(
    const float* __restrict__ csum, float* __restrict__ segT)
{
    const int seg = blockIdx.x, b = blockIdx.y, f = threadIdx.x;
    const float* p = csum + ((size_t)b * NCH + (size_t)seg * SEGL) * FF + f;
    float a = 0.f;
    #pragma unroll 8
    for (int i = 0; i < SEGL; ++i) a += p[(size_t)i * FF];
    segT[((size_t)b * NSEG + seg) * FF + f] = a;
}

// ---------------- K2b: exclusive scan of segment totals ----------------
__global__ __launch_bounds__(128) void k_segscan(float* __restrict__ segT)
{
    const int b = blockIdx.x, f = threadIdx.x;
    float acc = 0.f;
    for (int s = 0; s < NSEG; ++s) {
        size_t idx = ((size_t)b * NSEG + s) * FF + f;
        float v = segT[idx];
        segT[idx] = acc;
        acc += v;
    }
}

// ---------------- K2c: exclusive-ize chunk sums ----------------
__global__ __launch_bounds__(128) void k_chscan(
    float* __restrict__ csum, const float* __restrict__ segT)
{
    const int seg = blockIdx.x, b = blockIdx.y, f = threadIdx.x;
    float acc = segT[((size_t)b * NSEG + seg) * FF + f];
    float* p = csum + ((size_t)b * NCH + (size_t)seg * SEGL) * FF + f;
    #pragma unroll 8
    for (int i = 0; i < SEGL; ++i) {
        float v = p[(size_t)i * FF];
        p[(size_t)i * FF] = acc;
        acc += v;
    }
}

// ---------------- K3: scan + normalize + final dense (MFMA) ----------------
// 4 waves, wave = batch, fully wave-private (no __syncthreads).
// Phase A: lane = feature-pair; scan 16 positions, f16 store into
//          XOR-swizzled [16][128] tile (byte ^= (row&7)<<4).
// Phase B: A-frag = ds_read_b128; Y = mfma(A, Wf_frag); Q = diag(mfma(A, A));
//          q broadcast via ds_bpermute; masked scalar stores.
__global__ __launch_bounds__(256, 4) void k_final(
    const int* __restrict__ ex, const float* __restrict__ W_in,
    const float* __restrict__ b_in, const float* __restrict__ pos,
    const float* __restrict__ Wf, const float* __restrict__ bfin,
    const float* __restrict__ csum, float* __restrict__ out)
{
    __shared__ __align__(16) __half stile[BB][TL][FF];   // 16 KB
    __shared__ float xv[BB][CL];                          // 1.5 KB

    const int ch   = blockIdx.x;
    const int l0   = ch * CL;
    const int t    = threadIdx.x;
    const int b    = t >> 6;       // wave = batch
    const int lane = t & 63;
    const int lo   = lane & 15;
    const int hi   = lane >> 4;

    // stage xv for this wave's batch (wave-private)
    for (int i = lane; i < CL; i += 64)
        xv[b][i] = (float)ex[(size_t)b * LSEQ + l0 + i] * 0.5f - 3.0f;

    // Wf B-fragments (f16), cols >= 8 zeroed.  B layout: col=lane&15, k=(lane>>4)*8+j
    half8 wfrag[4];
    float bfc = (lo < CC) ? bfin[lo] : 0.f;
    #pragma unroll
    for (int kk = 0; kk < 4; ++kk) {
        #pragma unroll
        for (int j = 0; j < 8; ++j) {
            int k = kk * 32 + hi * 8 + j;
            float wv = (lo < CC) ? Wf[k * CC + lo] : 0.f;
            wfrag[kk][j] = (_Float16)wv;
        }
    }

    const float2 w  = *(const float2*)&W_in[2 * lane];
    const float2 bb = *(const float2*)&b_in[2 * lane];
    float2 s = *(const float2*)&csum[((size_t)b * NCH + ch) * FF + 2 * lane];

    char* sbase = (char*)&stile[b][0][0];
    // phase-B A-frag base byte offset (row = lo): kk advances via XOR of bit 6
    const int ra0 = lo * 256 + ((hi * 16) ^ ((lo & 7) << 4));
    const int wa  = 4 * lane;   // phase-A write offset before row-swizzle

    for (int tile = 0; tile < NT; ++tile) {
        // ---- phase A: scan TL positions, lane = feature-pair, 1 batch ----
        const float* pp = pos + (size_t)(l0 + tile * TL) * FF + 2 * lane;
        #pragma unroll
        for (int l = 0; l < TL; ++l) {
            float2 p = *(const float2*)pp; pp += FF;
            float x = xv[b][tile * TL + l];
            s.x = fmaxf(fmaf(x, w.x, p.x + bb.x), 0.f) + s.x;
            s.y = fmaxf(fmaf(x, w.y, p.y + bb.y), 0.f) + s.y;
            __half2 h = __float22half2_rn(make_float2(s.x, s.y));
            *(__half2*)(sbase + l * 256 + (wa ^ ((l & 7) << 4))) = h;
        }

        // ---- phase B: MFMA matvec + self-dot ----
        f32x4 y  = {0.f, 0.f, 0.f, 0.f};
        f32x4 c2 = {0.f, 0.f, 0.f, 0.f};
        #pragma unroll
        for (int kk = 0; kk < 4; ++kk) {
            half8 a = *(half8*)(sbase + (ra0 ^ (kk << 6)));
            y  = __builtin_amdgcn_mfma_f32_16x16x32_f16(a, wfrag[kk], y, 0, 0, 0);
            c2 = __builtin_amdgcn_mfma_f32_16x16x32_f16(a, a,        c2, 0, 0, 0);
        }

        // q = diag(C2): held by lanes with lo>>2 == hi at reg lo-4*hi
        int i0 = lo - 4 * hi;
        float qd = c2[0];
        qd = (i0 == 1) ? c2[1] : qd;
        qd = (i0 == 2) ? c2[2] : qd;
        qd = (i0 == 3) ? c2[3] : qd;
        float rr = rsqrtf(fmaxf(qd, 1e-12f));
        // rows 4*hi+i sourced from lane 20*hi+i
        int sl = 80 * hi;   // byte index = lane*4
        float r0 = __int_as_float(__builtin_amdgcn_ds_bpermute(sl,      __float_as_int(rr)));
        float r1 = __int_as_float(__builtin_amdgcn_ds_bpermute(sl + 4,  __float_as_int(rr)));
        float r2 = __int_as_float(__builtin_amdgcn_ds_bpermute(sl + 8,  __float_as_int(rr)));
        float r3 = __int_as_float(__builtin_amdgcn_ds_bpermute(sl + 12, __float_as_int(rr)));

        if (lo < CC) {
            float* op = out + (((size_t)b * LSEQ) + l0 + tile * TL) * CC + lo;
            op[(4 * hi + 0) * CC] = fmaf(y[0], r0, bfc);
            op[(4 * hi + 1) * CC] = fmaf(y[1], r1, bfc);
            op[(4 * hi + 2) * CC] = fmaf(y[2], r2, bfc);
            op[(4 * hi + 3) * CC] = fmaf(y[3], r3, bfc);
        }
    }
}

extern "C" void kernel_launch(void* const* d_in, const int* in_sizes, int n_in,
                              void* d_out, int out_size, void* d_ws, size_t ws_size,
                              hipStream_t stream) {
    const int*   ex   = (const int*)d_in[0];
    const float* W_in = (const float*)d_in[1];
    const float* b_in = (const float*)d_in[2];
    const float* pos  = (const float*)d_in[3];
    const float* Wf   = (const float*)d_in[4];
    const float* bf   = (const float*)d_in[5];
    float* out  = (float*)d_out;
    float* csum = (float*)d_ws;                       // [B][NCH][F]  = 4 MB
    float* segT = csum + (size_t)BB * NCH * FF;       // [B][NSEG][F] = 64 KB

    k_chunksum<<<NCH, 64, 0, stream>>>(ex, W_in, b_in, pos, csum);
    k_segsum  <<<dim3(NSEG, BB), 128, 0, stream>>>(csum, segT);
    k_segscan <<<BB, 128, 0, stream>>>(segT);
    k_chscan  <<<dim3(NSEG, BB), 128, 0, stream>>>(csum, segT);
    k_final   <<<NCH, 256, 0, stream>>>(ex, W_in, b_in, pos, Wf, bf, csum, out);
}

// Round 5
// 67.125 us; speedup vs baseline: 1.9461x; 1.0368x over previous
//
#include <hip/hip_runtime.h>
#include <hip/hip_fp16.h>

#define BB   4
#define FF   128
#define CC   8
#define LSEQ 196608        // 256*256*3
#define NCH  2048
#define CL   96            // LSEQ / NCH
#define TL   16            // positions per tile (= MFMA M)
#define NT   6             // CL / TL
#define NSEG 32
#define SEGL 64            // NCH / NSEG

typedef _Float16 half8 __attribute__((ext_vector_type(8)));
typedef float    f32x4 __attribute__((ext_vector_type(4)));

typedef const __attribute__((address_space(1))) void* gas_ptr;
typedef __attribute__((address_space(3))) void* las_ptr;

static __device__ __forceinline__ void ld_lds16(const void* g, void* l) {
    __builtin_amdgcn_global_load_lds((gas_ptr)g, (las_ptr)l, 16, 0, 0);
}

// ---------------- K1: per-chunk feature sums ----------------
__global__ __launch_bounds__(64) void k_chunksum(
    const int* __restrict__ ex, const float* __restrict__ W_in,
    const float* __restrict__ b_in, const float* __restrict__ pos,
    float* __restrict__ csum)
{
    __shared__ float xv[BB][CL];
    const int ch = blockIdx.x;
    const int t  = threadIdx.x;
    const int l0 = ch * CL;
    #pragma unroll
    for (int b = 0; b < BB; ++b)
        for (int i = t; i < CL; i += 64)
            xv[b][i] = (float)ex[(size_t)b * LSEQ + l0 + i] * 0.5f - 3.0f;
    __syncthreads();

    const float2 w  = *(const float2*)&W_in[2 * t];
    const float2 bb = *(const float2*)&b_in[2 * t];
    float2 s[BB];
    #pragma unroll
    for (int b = 0; b < BB; ++b) { s[b].x = 0.f; s[b].y = 0.f; }
    const float* pp = pos + (size_t)l0 * FF + 2 * t;
    #pragma unroll 4
    for (int l = 0; l < CL; ++l) {
        float2 p = *(const float2*)pp; pp += FF;
        float px = p.x + bb.x, py = p.y + bb.y;
        #pragma unroll
        for (int b = 0; b < BB; ++b) {
            float x = xv[b][l];
            s[b].x += fmaxf(fmaf(x, w.x, px), 0.f);
            s[b].y += fmaxf(fmaf(x, w.y, py), 0.f);
        }
    }
    #pragma unroll
    for (int b = 0; b < BB; ++b)
        *(float2*)&csum[((size_t)b * NCH + ch) * FF + 2 * t] = s[b];
}

// ---------------- K2a: segment totals ----------------
__global__ __launch_bounds__(128) void k_segsum(
    const float* __restrict__ csum, float* __restrict__ segT)
{
    const int seg = blockIdx.x, b = blockIdx.y, f = threadIdx.x;
    const float* p = csum + ((size_t)b * NCH + (size_t)seg * SEGL) * FF + f;
    float a = 0.f;
    #pragma unroll 8
    for (int i = 0; i < SEGL; ++i) a += p[(size_t)i * FF];
    segT[((size_t)b * NSEG + seg) * FF + f] = a;
}

// ---------------- K2b: exclusive scan of segment totals ----------------
__global__ __launch_bounds__(128) void k_segscan(float* __restrict__ segT)
{
    const int b = blockIdx.x, f = threadIdx.x;
    float acc = 0.f;
    for (int s = 0; s < NSEG; ++s) {
        size_t idx = ((size_t)b * NSEG + s) * FF + f;
        float v = segT[idx];
        segT[idx] = acc;
        acc += v;
    }
}

// ---------------- K2c: exclusive-ize chunk sums ----------------
__global__ __launch_bounds__(128) void k_chscan(
    float* __restrict__ csum, const float* __restrict__ segT)
{
    const int seg = blockIdx.x, b = blockIdx.y, f = threadIdx.x;
    float acc = segT[((size_t)b * NSEG + seg) * FF + f];
    float* p = csum + ((size_t)b * NCH + (size_t)seg * SEGL) * FF + f;
    #pragma unroll 8
    for (int i = 0; i < SEGL; ++i) {
        float v = p[(size_t)i * FF];
        p[(size_t)i * FF] = acc;
        acc += v;
    }
}

// ---------------- K3: scan + normalize + final dense (MFMA) ----------------
// 4 waves, wave = batch. pos tile staged ONCE per block into double-buffered
// LDS via global_load_lds (8x 1KB instrs, 2 per wave), issued at tile top so
// HBM/L3 latency hides under phase A (scan) + phase B (MFMA).
// Phase A: lane = feature-pair; scan 16 positions from pbuf, f16 store into
//          XOR-swizzled [16][128] tile (byte ^= (row&7)<<4).
// Phase B: A-frag = ds_read_b128; Y = mfma(A, Wf_frag); Q = diag(mfma(A, A));
//          q broadcast via ds_bpermute; masked scalar stores.
__global__ __launch_bounds__(256, 4) void k_final(
    const int* __restrict__ ex, const float* __restrict__ W_in,
    const float* __restrict__ b_in, const float* __restrict__ pos,
    const float* __restrict__ Wf, const float* __restrict__ bfin,
    const float* __restrict__ csum, float* __restrict__ out)
{
    __shared__ __align__(16) __half stile[BB][TL][FF];   // 16 KB
    __shared__ __align__(16) float  pbuf[2][TL][FF];     // 16 KB (dbuf)
    __shared__ float xv[BB][CL];                          // 1.5 KB

    const int ch   = blockIdx.x;
    const int l0   = ch * CL;
    const int t    = threadIdx.x;
    const int b    = t >> 6;       // wave = batch
    const int lane = t & 63;
    const int lo   = lane & 15;
    const int hi   = lane >> 4;

    // stage xv for this wave's batch (wave-private rows)
    for (int i = lane; i < CL; i += 64)
        xv[b][i] = (float)ex[(size_t)b * LSEQ + l0 + i] * 0.5f - 3.0f;

    // stage pos tile 0 into pbuf[0]: wave b stages rows {2b,2b+1,2b+8,2b+9}
    {
        const float* g1 = pos + (size_t)(l0 + 2 * b)     * FF + 4 * lane;
        const float* g2 = pos + (size_t)(l0 + 2 * b + 8) * FF + 4 * lane;
        ld_lds16(g1, &pbuf[0][2 * b][0]);
        ld_lds16(g2, &pbuf[0][2 * b + 8][0]);
    }

    // Wf B-fragments (f16), cols >= 8 zeroed.  B layout: col=lane&15, k=(lane>>4)*8+j
    half8 wfrag[4];
    float bfc = (lo < CC) ? bfin[lo] : 0.f;
    #pragma unroll
    for (int kk = 0; kk < 4; ++kk) {
        #pragma unroll
        for (int j = 0; j < 8; ++j) {
            int k = kk * 32 + hi * 8 + j;
            float wv = (lo < CC) ? Wf[k * CC + lo] : 0.f;
            wfrag[kk][j] = (_Float16)wv;
        }
    }

    const float2 w  = *(const float2*)&W_in[2 * lane];
    const float2 bb = *(const float2*)&b_in[2 * lane];
    float2 s = *(const float2*)&csum[((size_t)b * NCH + ch) * FF + 2 * lane];

    char* sbase = (char*)&stile[b][0][0];
    // phase-B A-frag base byte offset (row = lo): kk advances via XOR of bit 6
    const int ra0 = lo * 256 + ((hi * 16) ^ ((lo & 7) << 4));
    const int wa  = 4 * lane;   // phase-A write offset before row-swizzle

    __syncthreads();   // pbuf[0] ready (implicit vmcnt drain), xv ready

    int cur = 0;
    for (int tile = 0; tile < NT; ++tile) {
        // ---- prefetch next tile's pos into pbuf[cur^1] (overlaps A+B) ----
        if (tile + 1 < NT) {
            const int r0 = l0 + (tile + 1) * TL;
            const float* g1 = pos + (size_t)(r0 + 2 * b)     * FF + 4 * lane;
            const float* g2 = pos + (size_t)(r0 + 2 * b + 8) * FF + 4 * lane;
            ld_lds16(g1, &pbuf[cur ^ 1][2 * b][0]);
            ld_lds16(g2, &pbuf[cur ^ 1][2 * b + 8][0]);
        }

        // ---- phase A: scan TL positions, lane = feature-pair, 1 batch ----
        #pragma unroll
        for (int l = 0; l < TL; ++l) {
            float2 p = *(const float2*)&pbuf[cur][l][2 * lane];
            float x = xv[b][tile * TL + l];
            s.x = fmaxf(fmaf(x, w.x, p.x + bb.x), 0.f) + s.x;
            s.y = fmaxf(fmaf(x, w.y, p.y + bb.y), 0.f) + s.y;
            __half2 h = __float22half2_rn(make_float2(s.x, s.y));
            *(__half2*)(sbase + l * 256 + (wa ^ ((l & 7) << 4))) = h;
        }

        // ---- phase B: MFMA matvec + self-dot ----
        f32x4 y  = {0.f, 0.f, 0.f, 0.f};
        f32x4 c2 = {0.f, 0.f, 0.f, 0.f};
        #pragma unroll
        for (int kk = 0; kk < 4; ++kk) {
            half8 a = *(half8*)(sbase + (ra0 ^ (kk << 6)));
            y  = __builtin_amdgcn_mfma_f32_16x16x32_f16(a, wfrag[kk], y, 0, 0, 0);
            c2 = __builtin_amdgcn_mfma_f32_16x16x32_f16(a, a,        c2, 0, 0, 0);
        }

        // q = diag(C2): held by lanes with lo>>2 == hi at reg lo-4*hi
        int i0 = lo - 4 * hi;
        float qd = c2[0];
        qd = (i0 == 1) ? c2[1] : qd;
        qd = (i0 == 2) ? c2[2] : qd;
        qd = (i0 == 3) ? c2[3] : qd;
        float rr = rsqrtf(fmaxf(qd, 1e-12f));
        // rows 4*hi+i sourced from lane 20*hi+i
        int sl = 80 * hi;   // byte index = lane*4
        float r0 = __int_as_float(__builtin_amdgcn_ds_bpermute(sl,      __float_as_int(rr)));
        float r1 = __int_as_float(__builtin_amdgcn_ds_bpermute(sl + 4,  __float_as_int(rr)));
        float r2 = __int_as_float(__builtin_amdgcn_ds_bpermute(sl + 8,  __float_as_int(rr)));
        float r3 = __int_as_float(__builtin_amdgcn_ds_bpermute(sl + 12, __float_as_int(rr)));

        if (lo < CC) {
            float* op = out + (((size_t)b * LSEQ) + l0 + tile * TL) * CC + lo;
            op[(4 * hi + 0) * CC] = fmaf(y[0], r0, bfc);
            op[(4 * hi + 1) * CC] = fmaf(y[1], r1, bfc);
            op[(4 * hi + 2) * CC] = fmaf(y[2], r2, bfc);
            op[(4 * hi + 3) * CC] = fmaf(y[3], r3, bfc);
        }

        __syncthreads();   // drains this wave's global_load_lds; pbuf[cur^1] ready
        cur ^= 1;
    }
}

extern "C" void kernel_launch(void* const* d_in, const int* in_sizes, int n_in,
                              void* d_out, int out_size, void* d_ws, size_t ws_size,
                              hipStream_t stream) {
    const int*   ex   = (const int*)d_in[0];
    const float* W_in = (const float*)d_in[1];
    const float* b_in = (const float*)d_in[2];
    const float* pos  = (const float*)d_in[3];
    const float* Wf   = (const float*)d_in[4];
    const float* bf   = (const float*)d_in[5];
    float* out  = (float*)d_out;
    float* csum = (float*)d_ws;                       // [B][NCH][F]  = 4 MB
    float* segT = csum + (size_t)BB * NCH * FF;       // [B][NSEG][F] = 64 KB

    k_chunksum<<<NCH, 64, 0, stream>>>(ex, W_in, b_in, pos, csum);
    k_segsum  <<<dim3(NSEG, BB), 128, 0, stream>>>(csum, segT);
    k_segscan <<<BB, 128, 0, stream>>>(segT);
    k_chscan  <<<dim3(NSEG, BB), 128, 0, stream>>>(csum, segT);
    k_final   <<<NCH, 256, 0, stream>>>(ex, W_in, b_in, pos, Wf, bf, csum, out);
}